// Round 8
// baseline (28.698 us; speedup 1.0000x reference)
//
#include <hip/hip_runtime.h>
#include <cstdint>
#include <cmath>

#define N_WIRES 10
#define N_OPS 30
#define NG_FAST 40   // 30 random + 10 fused(RY*RX)
#define NG_SAFE 50   // 30 random + 10x(RX,RY) separate (R3-proven tail)
#define NG_MAX 50

typedef __attribute__((ext_vector_type(2))) float f2;   // (re, im) packed pair

// ---------------- compile-time numpy RandomState(42) replication -------------

struct CERng { uint32_t mt[624]; int mti; };

constexpr uint32_t ce_next32(CERng& r) {
  if (r.mti >= 624) {
    for (int i = 0; i < 624; ++i) {
      uint32_t y = (r.mt[i] & 0x80000000u) | (r.mt[(i + 1) % 624] & 0x7fffffffu);
      uint32_t v = r.mt[(i + 397) % 624] ^ (y >> 1);
      if (y & 1u) v ^= 2567483615u;
      r.mt[i] = v;
    }
    r.mti = 0;
  }
  uint32_t y = r.mt[r.mti++];
  y ^= y >> 11;
  y ^= (y << 7) & 2636928640u;
  y ^= (y << 15) & 4022730752u;
  y ^= y >> 18;
  return y;
}

constexpr uint32_t ce_masked(CERng& r, uint32_t rng) {  // legacy single-32b draw (R2-validated)
  if (rng == 0) return 0;
  uint32_t mask = rng;
  mask |= mask >> 1; mask |= mask >> 2; mask |= mask >> 4;
  mask |= mask >> 8; mask |= mask >> 16;
  uint32_t v = ce_next32(r) & mask;
  while (v > rng) v = ce_next32(r) & mask;
  return v;
}

// type: 0=rx 1=ry 2=rz 3=cnot 4=fused(RY*RX).  p0/p1 are BIT positions after remap.
struct Full { int n; int type[NG_MAX]; int p0[NG_MAX]; int p1[NG_MAX]; int aidx[NG_MAX]; int wbit[N_WIRES]; };

constexpr Full make_full(bool fused) {
  Full f{};
  int rty[N_OPS] = {}, rw0[N_OPS] = {}, rw1[N_OPS] = {};
  CERng r{};
  r.mt[0] = 42u;
  for (int i = 1; i < 624; ++i)
    r.mt[i] = 1812433253u * (r.mt[i - 1] ^ (r.mt[i - 1] >> 30)) + (uint32_t)i;
  r.mti = 624;
  for (int k = 0; k < N_OPS; ++k) {
    int g = (int)ce_masked(r, 3u);
    if (g == 3) {
      int arr[N_WIRES] = {0,1,2,3,4,5,6,7,8,9};
      for (int i = N_WIRES - 1; i >= 1; --i) {
        int j = (int)ce_masked(r, (uint32_t)i);
        int t = arr[i]; arr[i] = arr[j]; arr[j] = t;
      }
      rty[k] = 3; rw0[k] = arr[0]; rw1[k] = arr[1];
    } else {
      rty[k] = g; rw0[k] = (int)ce_masked(r, 9u); rw1[k] = -1;
    }
  }
  int cost[N_WIRES] = {};
  for (int k = 0; k < N_OPS; ++k) {
    if (rty[k] == 3) { cost[rw0[k]] += 1; cost[rw1[k]] += 2; }
    else if (rty[k] != 2) cost[rw0[k]] += 2;
  }
  for (int w = 0; w < N_WIRES; ++w) cost[w] += 2;
  int ord[N_WIRES] = {0,1,2,3,4,5,6,7,8,9};
  for (int i = 0; i < N_WIRES; ++i) {
    int best = i;
    for (int j = i + 1; j < N_WIRES; ++j)
      if (cost[ord[j]] > cost[ord[best]]) best = j;
    int t = ord[i]; ord[i] = ord[best]; ord[best] = t;
  }
  // hottest 4 -> register bits; lane bits: bit4/5=DPP 1-op (mask1/2),
  // bit8/9=permlane swap (mask16/32), bit6/7=ds_swizzle (mask4/8, DS pipe)
  f.wbit[ord[0]] = 3; f.wbit[ord[1]] = 2; f.wbit[ord[2]] = 1; f.wbit[ord[3]] = 0;
  f.wbit[ord[4]] = 4; f.wbit[ord[5]] = 5;
  f.wbit[ord[6]] = 8; f.wbit[ord[7]] = 9;
  f.wbit[ord[8]] = 6; f.wbit[ord[9]] = 7;
  for (int k = 0; k < N_OPS; ++k) {
    f.type[k] = rty[k];
    if (rty[k] == 3) { f.p0[k] = f.wbit[rw0[k]]; f.p1[k] = f.wbit[rw1[k]]; f.aidx[k] = 0; }
    else             { f.p0[k] = f.wbit[rw0[k]]; f.p1[k] = 0; f.aidx[k] = 10 + k; }
  }
  if (fused) {
    f.n = NG_FAST;
    for (int w = 0; w < N_WIRES; ++w) {
      f.type[N_OPS + w] = 4; f.p0[N_OPS + w] = f.wbit[w]; f.p1[N_OPS + w] = 0; f.aidx[N_OPS + w] = 0;
    }
  } else {
    f.n = NG_SAFE;
    for (int w = 0; w < N_WIRES; ++w) {
      f.type[N_OPS + 2*w]     = 0; f.p0[N_OPS + 2*w]     = f.wbit[w]; f.p1[N_OPS + 2*w]     = 0; f.aidx[N_OPS + 2*w]     = 40;
      f.type[N_OPS + 2*w + 1] = 1; f.p0[N_OPS + 2*w + 1] = f.wbit[w]; f.p1[N_OPS + 2*w + 1] = 0; f.aidx[N_OPS + 2*w + 1] = 41;
    }
  }
  return f;
}

constexpr Full FULLF = make_full(true);
constexpr Full FULLS = make_full(false);

constexpr int wire_at_bit(int bp) {
  for (int w = 0; w < N_WIRES; ++w) if (FULLF.wbit[w] == bp) return w;
  return 0;
}
constexpr int RW0 = wire_at_bit(0), RW1 = wire_at_bit(1), RW2 = wire_at_bit(2), RW3 = wire_at_bit(3);
constexpr int LW0 = wire_at_bit(4), LW1 = wire_at_bit(5), LW2 = wire_at_bit(6),
              LW3 = wire_at_bit(7), LW4 = wire_at_bit(8), LW5 = wire_at_bit(9);

// --------------------------------- device ------------------------------------

struct Ctx { int lane; bool s16, s32; }; // s16/s32: precomputed permlane result selects
// Fused 2x2 unitary, pk-ready form: xxij=(re,re), ynij=(-im,im) per entry.
struct U2p { f2 xx00, yn00, xx01, yn01, xx10, yn10, xx11, yn11; };

__device__ inline f2 fswap(f2 v) { return __builtin_shufflevector(v, v, 1, 0); }

// ---- guaranteed-packed VOP3P helpers (fast path = inline asm, probed) ----
template <bool SAFE>
__device__ inline f2 pk_mul(f2 a, f2 b) {
  if constexpr (SAFE) { return a * b; }
  else { f2 d; asm("v_pk_mul_f32 %0, %1, %2" : "=v"(d) : "v"(a), "v"(b)); return d; }
}
template <bool SAFE>
__device__ inline f2 pk_fma(f2 a, f2 b, f2 c) {   // a*b + c
  if constexpr (SAFE) { return a * b + c; }
  else { f2 d; asm("v_pk_fma_f32 %0, %1, %2, %3" : "=v"(d) : "v"(a), "v"(b), "v"(c)); return d; }
}
template <bool SAFE>
__device__ inline f2 pk_fma_swapb(f2 a, f2 b, f2 c) {   // a*swap(b) + c in ONE inst
  if constexpr (SAFE) { return a * fswap(b) + c; }
  else {
    f2 d;
    asm("v_pk_fma_f32 %0, %1, %2, %3 op_sel:[0,1,0] op_sel_hi:[1,0,1]"
        : "=v"(d) : "v"(a), "v"(b), "v"(c));
    return d;
  }
}
// complex mac: acc + u*a, u given as (xx, yn)
template <bool SAFE>
__device__ inline f2 cmadp(f2 xx, f2 yn, f2 a, f2 acc) {
  return pk_fma<SAFE>(xx, a, pk_fma_swapb<SAFE>(yn, a, acc));
}

template <bool SAFE>
__device__ inline float bcast(float x, int l) {
  if constexpr (SAFE) return __shfl(x, l, 64);
  else return __int_as_float(__builtin_amdgcn_readlane(__float_as_int(x), l));
}

// xor-exchange: mask1/2 = 1-op DPP; mask4/8 = ds_swizzle (DS pipe, overlaps VALU);
// mask16/32 = permlane swap + cndmask. SAFE => __shfl_xor (proven).
template <int MASK, bool SAFE>
__device__ inline float xshfl(float x, const Ctx& cx) {
  if constexpr (SAFE) {
    return __shfl_xor(x, MASK, 64);
  } else if constexpr (MASK == 1) {        // quad_perm [1,0,3,2] = xor1
    return __int_as_float(__builtin_amdgcn_update_dpp(0, __float_as_int(x), 0xB1, 0xF, 0xF, true));
  } else if constexpr (MASK == 2) {        // quad_perm [2,3,0,1] = xor2
    return __int_as_float(__builtin_amdgcn_update_dpp(0, __float_as_int(x), 0x4E, 0xF, 0xF, true));
  } else if constexpr (MASK == 4 || MASK == 8) {  // ds_swizzle xor-mode
    return __int_as_float(__builtin_amdgcn_ds_swizzle(__float_as_int(x), (MASK << 10) | 0x1F));
  } else if constexpr (MASK == 16) {
#if __has_builtin(__builtin_amdgcn_permlane16_swap)
    auto r = __builtin_amdgcn_permlane16_swap(__float_as_int(x), __float_as_int(x), false, false);
    return __int_as_float(cx.s16 ? r[0] : r[1]);
#else
    return __shfl_xor(x, 16, 64);
#endif
  } else {
#if __has_builtin(__builtin_amdgcn_permlane32_swap)
    auto r = __builtin_amdgcn_permlane32_swap(__float_as_int(x), __float_as_int(x), false, false);
    return __int_as_float(cx.s32 ? r[0] : r[1]);
#else
    return __shfl_xor(x, 32, 64);
#endif
  }
}

template <int MASK, bool SAFE>
__device__ inline f2 xshfl2(f2 v, const Ctx& cx) {
  f2 r;
  r.x = xshfl<MASK, SAFE>(v.x, cx);
  r.y = xshfl<MASK, SAFE>(v.y, cx);
  return r;
}

template <int TY, int P, bool SAFE>
__device__ inline void gate_local(f2 (&st)[16], float c, float s) {
  const f2 c2 = {c, c}, s2 = {s, s}, s2n = {-s, -s}, sn = {s, -s}, snn = {-s, s};
  #pragma unroll
  for (int b = 0; b < 16; ++b) {
    if ((b >> P) & 1) continue;
    const int i0 = b, i1 = b | (1 << P);
    const f2 a0 = st[i0], a1 = st[i1];
    if constexpr (TY == 0) {              // RX: c*a + (s,-s)*swap(partner)
      st[i0] = pk_fma_swapb<SAFE>(sn, a1, pk_mul<SAFE>(c2, a0));
      st[i1] = pk_fma_swapb<SAFE>(sn, a0, pk_mul<SAFE>(c2, a1));
    } else if constexpr (TY == 1) {       // RY: componentwise
      st[i0] = pk_fma<SAFE>(s2n, a1, pk_mul<SAFE>(c2, a0));
      st[i1] = pk_fma<SAFE>(s2,  a0, pk_mul<SAFE>(c2, a1));
    } else {                              // RZ: diagonal
      st[i0] = pk_fma_swapb<SAFE>(sn,  a0, pk_mul<SAFE>(c2, a0));
      st[i1] = pk_fma_swapb<SAFE>(snn, a1, pk_mul<SAFE>(c2, a1));
    }
  }
}

template <int TY, int LB, bool SAFE>
__device__ inline void gate_lane(f2 (&st)[16], float c, float s, const Ctx& cx) {
  const f2 c2 = {c, c};
  const bool hi = (cx.lane >> LB) & 1;
  if constexpr (TY == 2) {                // RZ: diagonal, no exchange
    const f2 sn = {s, -s}, snn = {-s, s};
    const f2 tn = hi ? snn : sn;
    #pragma unroll
    for (int j = 0; j < 16; ++j)
      st[j] = pk_fma_swapb<SAFE>(tn, st[j], pk_mul<SAFE>(c2, st[j]));
  } else if constexpr (TY == 0) {         // RX
    const f2 sn = {s, -s};
    #pragma unroll
    for (int j = 0; j < 16; ++j) {
      const f2 p = xshfl2<(1 << LB), SAFE>(st[j], cx);
      st[j] = pk_fma_swapb<SAFE>(sn, p, pk_mul<SAFE>(c2, st[j]));
    }
  } else {                                // RY
    const f2 s2 = {s, s}, s2n = {-s, -s};
    const f2 sg2 = hi ? s2 : s2n;
    #pragma unroll
    for (int j = 0; j < 16; ++j) {
      const f2 p = xshfl2<(1 << LB), SAFE>(st[j], cx);
      st[j] = pk_fma<SAFE>(sg2, p, pk_mul<SAFE>(c2, st[j]));
    }
  }
}

template <int P, bool SAFE>
__device__ inline void fused_local(f2 (&st)[16], const U2p& u) {
  #pragma unroll
  for (int b = 0; b < 16; ++b) {
    if ((b >> P) & 1) continue;
    const int i0 = b, i1 = b | (1 << P);
    const f2 a0 = st[i0], a1 = st[i1];
    const f2 t0 = pk_fma_swapb<SAFE>(u.yn00, a0, pk_mul<SAFE>(u.xx00, a0));
    st[i0] = cmadp<SAFE>(u.xx01, u.yn01, a1, t0);
    const f2 t1 = pk_fma_swapb<SAFE>(u.yn10, a0, pk_mul<SAFE>(u.xx10, a0));
    st[i1] = cmadp<SAFE>(u.xx11, u.yn11, a1, t1);
  }
}

template <int LB, bool SAFE>
__device__ inline void fused_lane(f2 (&st)[16], const U2p& u, const Ctx& cx) {
  const bool hi = (cx.lane >> LB) & 1;
  const f2 Axx = hi ? u.xx11 : u.xx00, Ayn = hi ? u.yn11 : u.yn00;
  const f2 Bxx = hi ? u.xx10 : u.xx01, Byn = hi ? u.yn10 : u.yn01;
  #pragma unroll
  for (int j = 0; j < 16; ++j) {
    const f2 p = xshfl2<(1 << LB), SAFE>(st[j], cx);
    const f2 t = pk_fma_swapb<SAFE>(Ayn, st[j], pk_mul<SAFE>(Axx, st[j]));
    st[j] = cmadp<SAFE>(Bxx, Byn, p, t);
  }
}

template <int CB, int TB, bool SAFE>
__device__ inline void cnot_gate(f2 (&st)[16], const Ctx& cx) {
  if constexpr (CB < 4 && TB < 4) {       // reg-reg: pure renaming
    #pragma unroll
    for (int b = 0; b < 16; ++b) {
      if (((b >> CB) & 1) && !((b >> TB) & 1)) {
        const int j = b | (1 << TB);
        const f2 t = st[b]; st[b] = st[j]; st[j] = t;
      }
    }
  } else if constexpr (CB < 4) {
    constexpr int M = 1 << (TB - 4);
    #pragma unroll
    for (int b = 0; b < 16; ++b) {
      if ((b >> CB) & 1) st[b] = xshfl2<M, SAFE>(st[b], cx);
    }
  } else if constexpr (TB < 4) {
    const bool cb = (cx.lane >> (CB - 4)) & 1;
    #pragma unroll
    for (int b = 0; b < 16; ++b) {
      if (!((b >> TB) & 1)) {
        const int j = b | (1 << TB);
        const f2 a0 = st[b], a1 = st[j];
        st[b] = cb ? a1 : a0; st[j] = cb ? a0 : a1;
      }
    }
  } else {
    const bool cb = (cx.lane >> (CB - 4)) & 1;
    constexpr int M = 1 << (TB - 4);
    #pragma unroll
    for (int j = 0; j < 16; ++j) {
      const f2 p = xshfl2<M, SAFE>(st[j], cx);
      st[j] = cb ? p : st[j];
    }
  }
}

template <int K, bool SAFE>
__device__ inline void run_gates(f2 (&st)[16], float tc, float ts, const U2p& u, const Ctx& cx) {
  constexpr int NG = SAFE ? NG_SAFE : NG_FAST;
  if constexpr (K < NG) {
    constexpr int ty = SAFE ? FULLS.type[K] : FULLF.type[K];
    constexpr int P0 = SAFE ? FULLS.p0[K]   : FULLF.p0[K];
    constexpr int P1 = SAFE ? FULLS.p1[K]   : FULLF.p1[K];
    constexpr int AI = SAFE ? FULLS.aidx[K] : FULLF.aidx[K];
    if constexpr (ty == 3) {
      cnot_gate<P0, P1, SAFE>(st, cx);
    } else if constexpr (ty == 4) {
      if constexpr (P0 < 4) fused_local<P0, SAFE>(st, u);
      else                  fused_lane<P0 - 4, SAFE>(st, u, cx);
    } else {
      const float c = bcast<SAFE>(tc, AI);
      const float s = bcast<SAFE>(ts, AI);
      if constexpr (P0 < 4) gate_local<ty, P0, SAFE>(st, c, s);
      else                  gate_lane<ty, P0 - 4, SAFE>(st, c, s, cx);
    }
    run_gates<K + 1, SAFE>(st, tc, ts, u, cx);
  }
}

template <bool SAFE>
__device__ inline void body(const Ctx& cx, int b, float tc, float ts,
                            const float* __restrict__ hw, const float* __restrict__ hb,
                            float* __restrict__ out) {
  const int lane = cx.lane;
  U2p u;
  {
    const float cxr = bcast<SAFE>(tc, 40), sxr = bcast<SAFE>(ts, 40);
    const float cyr = bcast<SAFE>(tc, 41), syr = bcast<SAFE>(ts, 41);
    // U = RY(ry)*RX(rx): u00=(cycx, sysx) u01=(-sycx, -cysx) u10=(sycx, -cysx) u11=(cycx, -sysx)
    const float r00 = cyr * cxr, i00 = syr * sxr;
    const float r01 = -syr * cxr, i01 = -cyr * sxr;
    const float r10 = syr * cxr, i10 = -cyr * sxr;
    const float r11 = cyr * cxr, i11 = -syr * sxr;
    u.xx00 = (f2){r00, r00}; u.yn00 = (f2){-i00, i00};
    u.xx01 = (f2){r01, r01}; u.yn01 = (f2){-i01, i01};
    u.xx10 = (f2){r10, r10}; u.yn10 = (f2){-i10, i10};
    u.xx11 = (f2){r11, r11}; u.yn11 = (f2){-i11, i11};
  }
  float ec[N_WIRES], es[N_WIRES];
  #pragma unroll
  for (int w = 0; w < N_WIRES; ++w) { ec[w] = bcast<SAFE>(tc, w); es[w] = bcast<SAFE>(ts, w); }

  float lp = ((lane >> 0) & 1) ? es[LW0] : ec[LW0];
  lp *= ((lane >> 1) & 1) ? es[LW1] : ec[LW1];
  lp *= ((lane >> 2) & 1) ? es[LW2] : ec[LW2];
  lp *= ((lane >> 3) & 1) ? es[LW3] : ec[LW3];
  lp *= ((lane >> 4) & 1) ? es[LW4] : ec[LW4];
  lp *= ((lane >> 5) & 1) ? es[LW5] : ec[LW5];
  f2 st[16];
  #pragma unroll
  for (int sl = 0; sl < 16; ++sl) {
    float a = lp;
    a *= (sl & 1) ? es[RW0] : ec[RW0];
    a *= (sl & 2) ? es[RW1] : ec[RW1];
    a *= (sl & 4) ? es[RW2] : ec[RW2];
    a *= (sl & 8) ? es[RW3] : ec[RW3];
    st[sl] = (f2){a, 0.0f};
  }

  run_gates<0, SAFE>(st, tc, ts, u, cx);

  float hwv[N_WIRES];
  #pragma unroll
  for (int w = 0; w < N_WIRES; ++w) hwv[w] = hw[w];
  float lw = (((lane >> 0) & 1) ? -hwv[LW0] : hwv[LW0])
           + (((lane >> 1) & 1) ? -hwv[LW1] : hwv[LW1])
           + (((lane >> 2) & 1) ? -hwv[LW2] : hwv[LW2])
           + (((lane >> 3) & 1) ? -hwv[LW3] : hwv[LW3])
           + (((lane >> 4) & 1) ? -hwv[LW4] : hwv[LW4])
           + (((lane >> 5) & 1) ? -hwv[LW5] : hwv[LW5]);
  float acc = 0.0f;
  #pragma unroll
  for (int sl = 0; sl < 16; ++sl) {
    float sw = lw;
    sw += (sl & 1) ? -hwv[RW0] : hwv[RW0];
    sw += (sl & 2) ? -hwv[RW1] : hwv[RW1];
    sw += (sl & 4) ? -hwv[RW2] : hwv[RW2];
    sw += (sl & 8) ? -hwv[RW3] : hwv[RW3];
    const f2 q = st[sl] * st[sl];
    acc += (q.x + q.y) * sw;
  }
  acc += xshfl<1,  SAFE>(acc, cx);
  acc += xshfl<2,  SAFE>(acc, cx);
  acc += xshfl<4,  SAFE>(acc, cx);
  acc += xshfl<8,  SAFE>(acc, cx);
  acc += xshfl<16, SAFE>(acc, cx);
  acc += xshfl<32, SAFE>(acc, cx);
  if (lane == 0) {
    const float logit = acc + hb[0] + 1.57079632679489662f;  // + SHIFT
    out[b] = 1.0f / (1.0f + expf(-logit));
  }
}

// cold fallback isolated from hot-path regalloc (rule #19)
__device__ __attribute__((noinline))
void body_safe(Ctx cx, int b, float tc, float ts,
               const float* __restrict__ hw, const float* __restrict__ hb,
               float* __restrict__ out) {
  body<true>(cx, b, tc, ts, hw, hb, out);
}

__global__ __launch_bounds__(256)
void qsim_kernel(const float* __restrict__ xb, const float* __restrict__ rxt,
                 const float* __restrict__ ryt, const float* __restrict__ rp,
                 const float* __restrict__ hw, const float* __restrict__ hb,
                 float* __restrict__ out, int bsz) {
  const int lane = threadIdx.x & 63;
  const int b = blockIdx.x * 4 + (threadIdx.x >> 6);  // one wave = one sample
  if (b >= bsz) return;

  float tc, ts;
  {
    float t = 0.0f;
    if (lane < 10)        t = xb[(size_t)b * 10 + lane];
    else if (lane < 40)   t = rp[lane - 10];
    else if (lane == 40)  t = rxt[0];
    else if (lane == 41)  t = ryt[0];
    float s, c;
    sincosf(0.5f * t, &s, &c);
    tc = c; ts = s;
  }

  // ---- mechanism self-test: exchanges AND packed-math asm, end-to-end ----
  Ctx cx; cx.lane = lane; cx.s16 = false; cx.s32 = false;
#if __has_builtin(__builtin_amdgcn_permlane16_swap)
  {
    auto r = __builtin_amdgcn_permlane16_swap(lane, lane, false, false);
    const bool f16 = (((lane & 16) ? r[0] : r[1]) != (lane ^ 16));
    cx.s16 = (((lane & 16) != 0) ^ f16);
  }
#endif
#if __has_builtin(__builtin_amdgcn_permlane32_swap)
  {
    auto r = __builtin_amdgcn_permlane32_swap(lane, lane, false, false);
    const bool f32 = (((lane & 32) ? r[0] : r[1]) != (lane ^ 32));
    cx.s32 = (((lane & 32) != 0) ^ f32);
  }
#endif
  bool ok = true;
  ok &= (__float_as_int(xshfl<1,  false>(__int_as_float(lane), cx)) == (lane ^ 1));
  ok &= (__float_as_int(xshfl<2,  false>(__int_as_float(lane), cx)) == (lane ^ 2));
  ok &= (__float_as_int(xshfl<4,  false>(__int_as_float(lane), cx)) == (lane ^ 4));
  ok &= (__float_as_int(xshfl<8,  false>(__int_as_float(lane), cx)) == (lane ^ 8));
  ok &= (__float_as_int(xshfl<16, false>(__int_as_float(lane), cx)) == (lane ^ 16));
  ok &= (__float_as_int(xshfl<32, false>(__int_as_float(lane), cx)) == (lane ^ 32));
  {
    // value-probe the asm pk helpers with exactly-representable ints
    const f2 pa = {1.f, 2.f}, pb = {3.f, 4.f}, pc = {5.f, 6.f};
    const f2 r1 = pk_mul<false>(pa, pb);            // (3, 8)
    const f2 r2 = pk_fma<false>(pa, pb, pc);        // (8, 14)
    const f2 r3 = pk_fma_swapb<false>(pa, pb, pc);  // (1*4+5, 2*3+6) = (9, 12)
    ok &= (r1.x == 3.f) & (r1.y == 8.f);
    ok &= (r2.x == 8.f) & (r2.y == 14.f);
    ok &= (r3.x == 9.f) & (r3.y == 12.f);
  }
  const bool fast = (__all((int)ok) != 0);

  if (fast) body<false>(cx, b, tc, ts, hw, hb, out);
  else      body_safe(cx, b, tc, ts, hw, hb, out);
}

// ---------------------------------- launch -----------------------------------

extern "C" void kernel_launch(void* const* d_in, const int* in_sizes, int n_in,
                              void* d_out, int out_size, void* d_ws, size_t ws_size,
                              hipStream_t stream) {
  const float* xb  = (const float*)d_in[0];
  const float* rxt = (const float*)d_in[1];
  const float* ryt = (const float*)d_in[2];
  const float* rp  = (const float*)d_in[3];
  const float* hw  = (const float*)d_in[4];
  const float* hb  = (const float*)d_in[5];
  float* out = (float*)d_out;

  const int bsz = in_sizes[0] / N_WIRES;
  const int nblk = (bsz + 3) / 4;

  hipLaunchKernelGGL(qsim_kernel, dim3(nblk), dim3(256), 0, stream,
                     xb, rxt, ryt, rp, hw, hb, out, bsz);
}

// Round 9
// 24.842 us; speedup vs baseline: 1.1552x; 1.1552x over previous
//
#include <hip/hip_runtime.h>
#include <cstdint>
#include <cmath>

#define N_WIRES 10
#define N_OPS 30
#define NG_FAST 40   // 30 random + 10 fused(RY*RX), tau-normalized
#define NG_SAFE 50   // 30 random + 10x(RX,RY) separate (R3-proven tail)
#define NG_MAX 50

typedef __attribute__((ext_vector_type(2))) float f2;   // (re, im) packed pair

// ---------------- compile-time numpy RandomState(42) replication -------------

struct CERng { uint32_t mt[624]; int mti; };

constexpr uint32_t ce_next32(CERng& r) {
  if (r.mti >= 624) {
    for (int i = 0; i < 624; ++i) {
      uint32_t y = (r.mt[i] & 0x80000000u) | (r.mt[(i + 1) % 624] & 0x7fffffffu);
      uint32_t v = r.mt[(i + 397) % 624] ^ (y >> 1);
      if (y & 1u) v ^= 2567483615u;
      r.mt[i] = v;
    }
    r.mti = 0;
  }
  uint32_t y = r.mt[r.mti++];
  y ^= y >> 11;
  y ^= (y << 7) & 2636928640u;
  y ^= (y << 15) & 4022730752u;
  y ^= y >> 18;
  return y;
}

constexpr uint32_t ce_masked(CERng& r, uint32_t rng) {  // legacy single-32b draw (R2-validated)
  if (rng == 0) return 0;
  uint32_t mask = rng;
  mask |= mask >> 1; mask |= mask >> 2; mask |= mask >> 4;
  mask |= mask >> 8; mask |= mask >> 16;
  uint32_t v = ce_next32(r) & mask;
  while (v > rng) v = ce_next32(r) & mask;
  return v;
}

// type: 0=rx 1=ry 2=rz 3=cnot 4=fused(RY*RX).  p0/p1 are BIT positions after remap.
struct Full { int n; int type[NG_MAX]; int p0[NG_MAX]; int p1[NG_MAX]; int aidx[NG_MAX]; int wbit[N_WIRES]; };

constexpr Full make_full(bool fused) {
  Full f{};
  int rty[N_OPS] = {}, rw0[N_OPS] = {}, rw1[N_OPS] = {};
  CERng r{};
  r.mt[0] = 42u;
  for (int i = 1; i < 624; ++i)
    r.mt[i] = 1812433253u * (r.mt[i - 1] ^ (r.mt[i - 1] >> 30)) + (uint32_t)i;
  r.mti = 624;
  for (int k = 0; k < N_OPS; ++k) {
    int g = (int)ce_masked(r, 3u);
    if (g == 3) {
      int arr[N_WIRES] = {0,1,2,3,4,5,6,7,8,9};
      for (int i = N_WIRES - 1; i >= 1; --i) {
        int j = (int)ce_masked(r, (uint32_t)i);
        int t = arr[i]; arr[i] = arr[j]; arr[j] = t;
      }
      rty[k] = 3; rw0[k] = arr[0]; rw1[k] = arr[1];
    } else {
      rty[k] = g; rw0[k] = (int)ce_masked(r, 9u); rw1[k] = -1;
    }
  }
  int cost[N_WIRES] = {};
  for (int k = 0; k < N_OPS; ++k) {
    if (rty[k] == 3) { cost[rw0[k]] += 1; cost[rw1[k]] += 2; }
    else if (rty[k] != 2) cost[rw0[k]] += 2;
  }
  for (int w = 0; w < N_WIRES; ++w) cost[w] += 2;
  int ord[N_WIRES] = {0,1,2,3,4,5,6,7,8,9};
  for (int i = 0; i < N_WIRES; ++i) {
    int best = i;
    for (int j = i + 1; j < N_WIRES; ++j)
      if (cost[ord[j]] > cost[ord[best]]) best = j;
    int t = ord[i]; ord[i] = ord[best]; ord[best] = t;
  }
  // hottest 4 -> register bits; lane bits: bit4/5=DPP(mask1/2),
  // bit8/9=permlane swap (mask16/32), bit6/7=ds_swizzle (mask4/8)
  f.wbit[ord[0]] = 3; f.wbit[ord[1]] = 2; f.wbit[ord[2]] = 1; f.wbit[ord[3]] = 0;
  f.wbit[ord[4]] = 4; f.wbit[ord[5]] = 5;
  f.wbit[ord[6]] = 8; f.wbit[ord[7]] = 9;
  f.wbit[ord[8]] = 6; f.wbit[ord[9]] = 7;
  for (int k = 0; k < N_OPS; ++k) {
    f.type[k] = rty[k];
    if (rty[k] == 3) { f.p0[k] = f.wbit[rw0[k]]; f.p1[k] = f.wbit[rw1[k]]; f.aidx[k] = 0; }
    else             { f.p0[k] = f.wbit[rw0[k]]; f.p1[k] = 0; f.aidx[k] = 10 + k; }
  }
  if (fused) {
    f.n = NG_FAST;
    for (int w = 0; w < N_WIRES; ++w) {
      f.type[N_OPS + w] = 4; f.p0[N_OPS + w] = f.wbit[w]; f.p1[N_OPS + w] = 0; f.aidx[N_OPS + w] = 0;
    }
  } else {
    f.n = NG_SAFE;
    for (int w = 0; w < N_WIRES; ++w) {
      f.type[N_OPS + 2*w]     = 0; f.p0[N_OPS + 2*w]     = f.wbit[w]; f.p1[N_OPS + 2*w]     = 0; f.aidx[N_OPS + 2*w]     = 40;
      f.type[N_OPS + 2*w + 1] = 1; f.p0[N_OPS + 2*w + 1] = f.wbit[w]; f.p1[N_OPS + 2*w + 1] = 0; f.aidx[N_OPS + 2*w + 1] = 41;
    }
  }
  return f;
}

constexpr Full FULLF = make_full(true);
constexpr Full FULLS = make_full(false);

constexpr int wire_at_bit(int bp) {
  for (int w = 0; w < N_WIRES; ++w) if (FULLF.wbit[w] == bp) return w;
  return 0;
}
constexpr int RW0 = wire_at_bit(0), RW1 = wire_at_bit(1), RW2 = wire_at_bit(2), RW3 = wire_at_bit(3);
constexpr int LW0 = wire_at_bit(4), LW1 = wire_at_bit(5), LW2 = wire_at_bit(6),
              LW3 = wire_at_bit(7), LW4 = wire_at_bit(8), LW5 = wire_at_bit(9);

// --------------------------------- device ------------------------------------

struct Ctx { int lane; bool s16, s32; };            // permlane result selects
struct U2t { float ty, tx, A, s; };                 // tau-form tail: V = U/(cy*cx)

__device__ inline f2 fswap(f2 v) { return __builtin_shufflevector(v, v, 1, 0); }

template <bool SAFE>
__device__ inline float bcast(float x, int l) {
  if constexpr (SAFE) return __shfl(x, l, 64);
  else return __int_as_float(__builtin_amdgcn_readlane(__float_as_int(x), l));
}

// xor-exchange (R6-proven): mask1/2 DPP, mask4/8 ds_swizzle, mask16/32 permlane+sel
template <int MASK, bool SAFE>
__device__ inline float xshfl(float x, const Ctx& cx) {
  if constexpr (SAFE) {
    return __shfl_xor(x, MASK, 64);
  } else if constexpr (MASK == 1) {
    return __int_as_float(__builtin_amdgcn_update_dpp(0, __float_as_int(x), 0xB1, 0xF, 0xF, true));
  } else if constexpr (MASK == 2) {
    return __int_as_float(__builtin_amdgcn_update_dpp(0, __float_as_int(x), 0x4E, 0xF, 0xF, true));
  } else if constexpr (MASK == 4 || MASK == 8) {
    return __int_as_float(__builtin_amdgcn_ds_swizzle(__float_as_int(x), (MASK << 10) | 0x1F));
  } else if constexpr (MASK == 16) {
#if __has_builtin(__builtin_amdgcn_permlane16_swap)
    auto r = __builtin_amdgcn_permlane16_swap(__float_as_int(x), __float_as_int(x), false, false);
    return __int_as_float(cx.s16 ? r[0] : r[1]);
#else
    return __shfl_xor(x, 16, 64);
#endif
  } else {
#if __has_builtin(__builtin_amdgcn_permlane32_swap)
    auto r = __builtin_amdgcn_permlane32_swap(__float_as_int(x), __float_as_int(x), false, false);
    return __int_as_float(cx.s32 ? r[0] : r[1]);
#else
    return __shfl_xor(x, 32, 64);
#endif
  }
}

template <int MASK, bool SAFE>
__device__ inline f2 xshfl2(f2 v, const Ctx& cx) {
  f2 r;
  r.x = xshfl<MASK, SAFE>(v.x, cx);
  r.y = xshfl<MASK, SAFE>(v.y, cx);
  return r;
}

// ---------------- FAST gates: tau-normalized (1 fma per slot-term) ----------

template <int TY, int P>
__device__ inline void gate_local_tau(f2 (&st)[16], float tau) {
  const f2 tn = {tau, -tau}, tnn = {-tau, tau}, tp = {tau, tau}, tm = {-tau, -tau};
  #pragma unroll
  for (int b = 0; b < 16; ++b) {
    if ((b >> P) & 1) continue;
    const int i0 = b, i1 = b | (1 << P);
    const f2 a0 = st[i0], a1 = st[i1];
    if constexpr (TY == 0) {              // RX/c: a' = a - i*tau*partner
      st[i0] = a0 + tn * fswap(a1);
      st[i1] = a1 + tn * fswap(a0);
    } else if constexpr (TY == 1) {       // RY/c
      st[i0] = a0 + tm * a1;
      st[i1] = a1 + tp * a0;
    } else {                              // RZ/c: (1 -/+ i*tau) diagonal
      st[i0] = a0 + tn  * fswap(a0);
      st[i1] = a1 + tnn * fswap(a1);
    }
  }
}

template <int TY, int LB>
__device__ inline void gate_lane_tau(f2 (&st)[16], float tau, const Ctx& cx) {
  const bool hi = (cx.lane >> LB) & 1;
  if constexpr (TY == 2) {                // RZ: diagonal, no exchange
    const f2 tsel = hi ? (f2){-tau, tau} : (f2){tau, -tau};
    #pragma unroll
    for (int j = 0; j < 16; ++j) st[j] = st[j] + tsel * fswap(st[j]);
  } else if constexpr (TY == 0) {         // RX: symmetric
    const f2 tn = {tau, -tau};
    #pragma unroll
    for (int j = 0; j < 16; ++j) {
      const f2 p = xshfl2<(1 << LB), false>(st[j], cx);
      st[j] = st[j] + tn * fswap(p);
    }
  } else {                                // RY: sign per side
    const f2 sg = hi ? (f2){tau, tau} : (f2){-tau, -tau};
    #pragma unroll
    for (int j = 0; j < 16; ++j) {
      const f2 p = xshfl2<(1 << LB), false>(st[j], cx);
      st[j] = st[j] + sg * p;
    }
  }
}

// tail V = RY*RX/(cy*cx): v00=1+iA v01=-ty-i*tx v10=ty-i*tx v11=1-iA, A=ty*tx
template <int P>
__device__ inline void fused_local_tau(f2 (&st)[16], const U2t& u) {
  const f2 Tm = {-u.ty, -u.ty}, Tp = {u.ty, u.ty};
  const f2 An = {-u.A, u.A}, Ap = {u.A, -u.A};
  const f2 Xs = {u.tx, -u.tx};
  #pragma unroll
  for (int b = 0; b < 16; ++b) {
    if ((b >> P) & 1) continue;
    const int i0 = b, i1 = b | (1 << P);
    const f2 a0 = st[i0], a1 = st[i1];
    f2 o0 = a0 + Tm * a1;
    o0 = o0 + An * fswap(a0);
    o0 = o0 + Xs * fswap(a1);
    f2 o1 = a1 + Tp * a0;
    o1 = o1 + Ap * fswap(a1);
    o1 = o1 + Xs * fswap(a0);
    st[i0] = o0; st[i1] = o1;
  }
}

template <int LB>
__device__ inline void fused_lane_tau(f2 (&st)[16], const U2t& u, const Ctx& cx) {
  const bool hi = (cx.lane >> LB) & 1;
  const f2 Tp  = hi ? (f2){u.ty, u.ty} : (f2){-u.ty, -u.ty};
  const f2 Tst = hi ? (f2){u.A, -u.A}  : (f2){-u.A, u.A};
  const f2 Xs  = {u.tx, -u.tx};
  #pragma unroll
  for (int j = 0; j < 16; ++j) {
    const f2 p = xshfl2<(1 << LB), false>(st[j], cx);
    f2 o = st[j] + Tp * p;
    o = o + Tst * fswap(st[j]);
    o = o + Xs * fswap(p);
    st[j] = o;
  }
}

// ---------------- SAFE gates: classic c,s form (R3/R6-proven) ----------------

template <int TY, int P>
__device__ inline void gate_local_cs(f2 (&st)[16], float c, float s) {
  const f2 c2 = {c, c}, s2 = {s, s}, sn = {s, -s};
  #pragma unroll
  for (int b = 0; b < 16; ++b) {
    if ((b >> P) & 1) continue;
    const int i0 = b, i1 = b | (1 << P);
    const f2 a0 = st[i0], a1 = st[i1];
    if constexpr (TY == 0) {
      st[i0] = c2 * a0 + sn * fswap(a1);
      st[i1] = c2 * a1 + sn * fswap(a0);
    } else if constexpr (TY == 1) {
      st[i0] = c2 * a0 - s2 * a1;
      st[i1] = c2 * a1 + s2 * a0;
    } else {
      st[i0] = c2 * a0 + sn * fswap(a0);
      st[i1] = c2 * a1 - sn * fswap(a1);
    }
  }
}

template <int TY, int LB>
__device__ inline void gate_lane_cs(f2 (&st)[16], float c, float s, const Ctx& cx) {
  const f2 c2 = {c, c};
  if constexpr (TY == 2) {
    const float t = ((cx.lane >> LB) & 1) ? -s : s;
    const f2 tn = {t, -t};
    #pragma unroll
    for (int j = 0; j < 16; ++j) st[j] = c2 * st[j] + tn * fswap(st[j]);
  } else if constexpr (TY == 0) {
    const f2 sn = {s, -s};
    #pragma unroll
    for (int j = 0; j < 16; ++j) {
      const f2 p = xshfl2<(1 << LB), true>(st[j], cx);
      st[j] = c2 * st[j] + sn * fswap(p);
    }
  } else {
    const float sg = ((cx.lane >> LB) & 1) ? s : -s;
    const f2 sg2 = {sg, sg};
    #pragma unroll
    for (int j = 0; j < 16; ++j) {
      const f2 p = xshfl2<(1 << LB), true>(st[j], cx);
      st[j] = c2 * st[j] + sg2 * p;
    }
  }
}

// ---------------- CNOT (both paths) ----------------

template <int CB, int TB, bool SAFE>
__device__ inline void cnot_gate(f2 (&st)[16], const Ctx& cx) {
  if constexpr (CB < 4 && TB < 4) {
    #pragma unroll
    for (int b = 0; b < 16; ++b) {
      if (((b >> CB) & 1) && !((b >> TB) & 1)) {
        const int j = b | (1 << TB);
        const f2 t = st[b]; st[b] = st[j]; st[j] = t;
      }
    }
  } else if constexpr (CB < 4) {
    constexpr int M = 1 << (TB - 4);
    #pragma unroll
    for (int b = 0; b < 16; ++b) {
      if ((b >> CB) & 1) st[b] = xshfl2<M, SAFE>(st[b], cx);
    }
  } else if constexpr (TB < 4) {
    const bool cb = (cx.lane >> (CB - 4)) & 1;
    #pragma unroll
    for (int b = 0; b < 16; ++b) {
      if (!((b >> TB) & 1)) {
        const int j = b | (1 << TB);
        const f2 a0 = st[b], a1 = st[j];
        st[b] = cb ? a1 : a0; st[j] = cb ? a0 : a1;
      }
    }
  } else {
    const bool cb = (cx.lane >> (CB - 4)) & 1;
    constexpr int M = 1 << (TB - 4);
    #pragma unroll
    for (int j = 0; j < 16; ++j) {
      const f2 p = xshfl2<M, SAFE>(st[j], cx);
      st[j] = cb ? p : st[j];
    }
  }
}

// ---------------- circuit driver ----------------

template <int K, bool SAFE>
__device__ inline void run_gates(f2 (&st)[16], float tc, float ts, const U2t& u,
                                 const Ctx& cx, float& scale) {
  constexpr int NG = SAFE ? NG_SAFE : NG_FAST;
  if constexpr (K < NG) {
    constexpr int ty = SAFE ? FULLS.type[K] : FULLF.type[K];
    constexpr int P0 = SAFE ? FULLS.p0[K]   : FULLF.p0[K];
    constexpr int P1 = SAFE ? FULLS.p1[K]   : FULLF.p1[K];
    constexpr int AI = SAFE ? FULLS.aidx[K] : FULLF.aidx[K];
    if constexpr (ty == 3) {
      cnot_gate<P0, P1, SAFE>(st, cx);
    } else if constexpr (ty == 4) {       // fast path only
      scale *= u.s;
      if constexpr (P0 < 4) fused_local_tau<P0>(st, u);
      else                  fused_lane_tau<P0 - 4>(st, u, cx);
    } else if constexpr (SAFE) {
      const float c = bcast<true>(tc, AI);
      const float s = bcast<true>(ts, AI);
      if constexpr (P0 < 4) gate_local_cs<ty, P0>(st, c, s);
      else                  gate_lane_cs<ty, P0 - 4>(st, c, s, cx);
    } else {
      const float c = bcast<false>(tc, AI);
      const float s = bcast<false>(ts, AI);
      const float tau = s * __builtin_amdgcn_rcpf(c);
      scale *= c;
      if constexpr (P0 < 4) gate_local_tau<ty, P0>(st, tau);
      else                  gate_lane_tau<ty, P0 - 4>(st, tau, cx);
    }
    run_gates<K + 1, SAFE>(st, tc, ts, u, cx, scale);
  }
}

template <bool SAFE>
__device__ inline void body(const Ctx& cx, int b, float tc, float ts,
                            const float* __restrict__ hw, const float* __restrict__ hb,
                            float* __restrict__ out) {
  const int lane = cx.lane;
  U2t u;
  {
    const float cxr = bcast<SAFE>(tc, 40), sxr = bcast<SAFE>(ts, 40);
    const float cyr = bcast<SAFE>(tc, 41), syr = bcast<SAFE>(ts, 41);
    u.tx = sxr * __builtin_amdgcn_rcpf(cxr);
    u.ty = syr * __builtin_amdgcn_rcpf(cyr);
    u.A = u.ty * u.tx;
    u.s = cyr * cxr;
  }
  float ec[N_WIRES], es[N_WIRES];
  #pragma unroll
  for (int w = 0; w < N_WIRES; ++w) { ec[w] = bcast<SAFE>(tc, w); es[w] = bcast<SAFE>(ts, w); }

  float lp = ((lane >> 0) & 1) ? es[LW0] : ec[LW0];
  lp *= ((lane >> 1) & 1) ? es[LW1] : ec[LW1];
  lp *= ((lane >> 2) & 1) ? es[LW2] : ec[LW2];
  lp *= ((lane >> 3) & 1) ? es[LW3] : ec[LW3];
  lp *= ((lane >> 4) & 1) ? es[LW4] : ec[LW4];
  lp *= ((lane >> 5) & 1) ? es[LW5] : ec[LW5];
  f2 st[16];
  #pragma unroll
  for (int sl = 0; sl < 16; ++sl) {
    float a = lp;
    a *= (sl & 1) ? es[RW0] : ec[RW0];
    a *= (sl & 2) ? es[RW1] : ec[RW1];
    a *= (sl & 4) ? es[RW2] : ec[RW2];
    a *= (sl & 8) ? es[RW3] : ec[RW3];
    st[sl] = (f2){a, 0.0f};
  }

  float scale = 1.0f;
  run_gates<0, SAFE>(st, tc, ts, u, cx, scale);

  float hwv[N_WIRES];
  #pragma unroll
  for (int w = 0; w < N_WIRES; ++w) hwv[w] = hw[w];
  float lw = (((lane >> 0) & 1) ? -hwv[LW0] : hwv[LW0])
           + (((lane >> 1) & 1) ? -hwv[LW1] : hwv[LW1])
           + (((lane >> 2) & 1) ? -hwv[LW2] : hwv[LW2])
           + (((lane >> 3) & 1) ? -hwv[LW3] : hwv[LW3])
           + (((lane >> 4) & 1) ? -hwv[LW4] : hwv[LW4])
           + (((lane >> 5) & 1) ? -hwv[LW5] : hwv[LW5]);
  float acc = 0.0f;
  #pragma unroll
  for (int sl = 0; sl < 16; ++sl) {
    float sw = lw;
    sw += (sl & 1) ? -hwv[RW0] : hwv[RW0];
    sw += (sl & 2) ? -hwv[RW1] : hwv[RW1];
    sw += (sl & 4) ? -hwv[RW2] : hwv[RW2];
    sw += (sl & 8) ? -hwv[RW3] : hwv[RW3];
    const f2 q = st[sl] * st[sl];
    acc += (q.x + q.y) * sw;
  }
  if constexpr (!SAFE) {
    const float S2 = scale * scale;   // restore deferred gate scalars: |amp|^2 * (Pi c)^2
    acc *= S2;
  }
  acc += xshfl<1,  SAFE>(acc, cx);
  acc += xshfl<2,  SAFE>(acc, cx);
  acc += xshfl<4,  SAFE>(acc, cx);
  acc += xshfl<8,  SAFE>(acc, cx);
  acc += xshfl<16, SAFE>(acc, cx);
  acc += xshfl<32, SAFE>(acc, cx);
  if (lane == 0) {
    const float logit = acc + hb[0] + 1.57079632679489662f;  // + SHIFT
    out[b] = 1.0f / (1.0f + expf(-logit));
  }
}

// cold fallback isolated from hot-path regalloc
__device__ __attribute__((noinline))
void body_safe(Ctx cx, int b, float tc, float ts,
               const float* __restrict__ hw, const float* __restrict__ hb,
               float* __restrict__ out) {
  body<true>(cx, b, tc, ts, hw, hb, out);
}

__global__ __launch_bounds__(256)
void qsim_kernel(const float* __restrict__ xb, const float* __restrict__ rxt,
                 const float* __restrict__ ryt, const float* __restrict__ rp,
                 const float* __restrict__ hw, const float* __restrict__ hb,
                 float* __restrict__ out, int bsz) {
  const int lane = threadIdx.x & 63;
  const int b = blockIdx.x * 4 + (threadIdx.x >> 6);  // one wave = one sample
  if (b >= bsz) return;

  float tc, ts;
  {
    float t = 0.0f;
    if (lane < 10)        t = xb[(size_t)b * 10 + lane];
    else if (lane < 40)   t = rp[lane - 10];
    else if (lane == 40)  t = rxt[0];
    else if (lane == 41)  t = ryt[0];
    float s, c;
    sincosf(0.5f * t, &s, &c);
    tc = c; ts = s;
  }

  // ---- mechanism self-test: orientation probes + end-to-end validation ----
  Ctx cx; cx.lane = lane; cx.s16 = false; cx.s32 = false;
#if __has_builtin(__builtin_amdgcn_permlane16_swap)
  {
    auto r = __builtin_amdgcn_permlane16_swap(lane, lane, false, false);
    const bool f16 = (((lane & 16) ? r[0] : r[1]) != (lane ^ 16));
    cx.s16 = (((lane & 16) != 0) ^ f16);
  }
#endif
#if __has_builtin(__builtin_amdgcn_permlane32_swap)
  {
    auto r = __builtin_amdgcn_permlane32_swap(lane, lane, false, false);
    const bool f32 = (((lane & 32) ? r[0] : r[1]) != (lane ^ 32));
    cx.s32 = (((lane & 32) != 0) ^ f32);
  }
#endif
  bool ok = true;
  ok &= (__float_as_int(xshfl<1,  false>(__int_as_float(lane), cx)) == (lane ^ 1));
  ok &= (__float_as_int(xshfl<2,  false>(__int_as_float(lane), cx)) == (lane ^ 2));
  ok &= (__float_as_int(xshfl<4,  false>(__int_as_float(lane), cx)) == (lane ^ 4));
  ok &= (__float_as_int(xshfl<8,  false>(__int_as_float(lane), cx)) == (lane ^ 8));
  ok &= (__float_as_int(xshfl<16, false>(__int_as_float(lane), cx)) == (lane ^ 16));
  ok &= (__float_as_int(xshfl<32, false>(__int_as_float(lane), cx)) == (lane ^ 32));
  const bool fast = (__all((int)ok) != 0);

  if (fast) body<false>(cx, b, tc, ts, hw, hb, out);
  else      body_safe(cx, b, tc, ts, hw, hb, out);
}

// ---------------------------------- launch -----------------------------------

extern "C" void kernel_launch(void* const* d_in, const int* in_sizes, int n_in,
                              void* d_out, int out_size, void* d_ws, size_t ws_size,
                              hipStream_t stream) {
  const float* xb  = (const float*)d_in[0];
  const float* rxt = (const float*)d_in[1];
  const float* ryt = (const float*)d_in[2];
  const float* rp  = (const float*)d_in[3];
  const float* hw  = (const float*)d_in[4];
  const float* hb  = (const float*)d_in[5];
  float* out = (float*)d_out;

  const int bsz = in_sizes[0] / N_WIRES;
  const int nblk = (bsz + 3) / 4;

  hipLaunchKernelGGL(qsim_kernel, dim3(nblk), dim3(256), 0, stream,
                     xb, rxt, ryt, rp, hw, hb, out, bsz);
}

// Round 10
// 19.153 us; speedup vs baseline: 1.4984x; 1.2970x over previous
//
#include <hip/hip_runtime.h>
#include <cstdint>
#include <cmath>

#define N_WIRES 10
#define N_OPS 30
#define NG_SAFE 50
#define NG_MAX 50

typedef __attribute__((ext_vector_type(2))) float f2;   // (re, im) packed pair

// ---------------- compile-time numpy RandomState(42) replication -------------

struct CERng { uint32_t mt[624]; int mti; };

constexpr uint32_t ce_next32(CERng& r) {
  if (r.mti >= 624) {
    for (int i = 0; i < 624; ++i) {
      uint32_t y = (r.mt[i] & 0x80000000u) | (r.mt[(i + 1) % 624] & 0x7fffffffu);
      uint32_t v = r.mt[(i + 397) % 624] ^ (y >> 1);
      if (y & 1u) v ^= 2567483615u;
      r.mt[i] = v;
    }
    r.mti = 0;
  }
  uint32_t y = r.mt[r.mti++];
  y ^= y >> 11;
  y ^= (y << 7) & 2636928640u;
  y ^= (y << 15) & 4022730752u;
  y ^= y >> 18;
  return y;
}

constexpr uint32_t ce_masked(CERng& r, uint32_t rng) {  // legacy single-32b draw (R2-validated)
  if (rng == 0) return 0;
  uint32_t mask = rng;
  mask |= mask >> 1; mask |= mask >> 2; mask |= mask >> 4;
  mask |= mask >> 8; mask |= mask >> 16;
  uint32_t v = ce_next32(r) & mask;
  while (v > rng) v = ce_next32(r) & mask;
  return v;
}

struct RawSpec { int ty[N_OPS]; int w0[N_OPS]; int w1[N_OPS]; };

constexpr RawSpec make_raw() {
  RawSpec s{};
  CERng r{};
  r.mt[0] = 42u;
  for (int i = 1; i < 624; ++i)
    r.mt[i] = 1812433253u * (r.mt[i - 1] ^ (r.mt[i - 1] >> 30)) + (uint32_t)i;
  r.mti = 624;
  for (int k = 0; k < N_OPS; ++k) {
    int g = (int)ce_masked(r, 3u);
    if (g == 3) {
      int arr[N_WIRES] = {0,1,2,3,4,5,6,7,8,9};
      for (int i = N_WIRES - 1; i >= 1; --i) {
        int j = (int)ce_masked(r, (uint32_t)i);
        int t = arr[i]; arr[i] = arr[j]; arr[j] = t;
      }
      s.ty[k] = 3; s.w0[k] = arr[0]; s.w1[k] = arr[1];
    } else {
      s.ty[k] = g; s.w0[k] = (int)ce_masked(r, 9u); s.w1[k] = -1;
    }
  }
  return s;
}

constexpr RawSpec RAW = make_raw();

// ---------------- SAFE program (R9-proven, untransformed) --------------------
// type: 0=rx 1=ry 2=rz 3=cnot.  p0/p1 are BIT positions after remap.
struct Full { int type[NG_MAX]; int p0[NG_MAX]; int p1[NG_MAX]; int aidx[NG_MAX]; int wbit[N_WIRES]; };

constexpr Full make_safe() {
  Full f{};
  int cost[N_WIRES] = {};
  for (int k = 0; k < N_OPS; ++k) {
    if (RAW.ty[k] == 3) { cost[RAW.w0[k]] += 1; cost[RAW.w1[k]] += 2; }
    else if (RAW.ty[k] != 2) cost[RAW.w0[k]] += 2;
  }
  for (int w = 0; w < N_WIRES; ++w) cost[w] += 2;
  int ord[N_WIRES] = {0,1,2,3,4,5,6,7,8,9};
  for (int i = 0; i < N_WIRES; ++i) {
    int best = i;
    for (int j = i + 1; j < N_WIRES; ++j)
      if (cost[ord[j]] > cost[ord[best]]) best = j;
    int t = ord[i]; ord[i] = ord[best]; ord[best] = t;
  }
  f.wbit[ord[0]] = 3; f.wbit[ord[1]] = 2; f.wbit[ord[2]] = 1; f.wbit[ord[3]] = 0;
  f.wbit[ord[4]] = 4; f.wbit[ord[5]] = 5;
  f.wbit[ord[6]] = 8; f.wbit[ord[7]] = 9;
  f.wbit[ord[8]] = 6; f.wbit[ord[9]] = 7;
  for (int k = 0; k < N_OPS; ++k) {
    f.type[k] = RAW.ty[k];
    if (RAW.ty[k] == 3) { f.p0[k] = f.wbit[RAW.w0[k]]; f.p1[k] = f.wbit[RAW.w1[k]]; f.aidx[k] = 0; }
    else                { f.p0[k] = f.wbit[RAW.w0[k]]; f.p1[k] = 0; f.aidx[k] = 10 + k; }
  }
  for (int w = 0; w < N_WIRES; ++w) {
    f.type[N_OPS + 2*w]     = 0; f.p0[N_OPS + 2*w]     = f.wbit[w]; f.p1[N_OPS + 2*w]     = 0; f.aidx[N_OPS + 2*w]     = 40;
    f.type[N_OPS + 2*w + 1] = 1; f.p0[N_OPS + 2*w + 1] = f.wbit[w]; f.p1[N_OPS + 2*w + 1] = 0; f.aidx[N_OPS + 2*w + 1] = 41;
  }
  return f;
}

constexpr Full FULLS = make_safe();

constexpr int s_wire_at_bit(int bp) {
  for (int w = 0; w < N_WIRES; ++w) if (FULLS.wbit[w] == bp) return w;
  return 0;
}
constexpr int SRW0 = s_wire_at_bit(0), SRW1 = s_wire_at_bit(1), SRW2 = s_wire_at_bit(2), SRW3 = s_wire_at_bit(3);
constexpr int SLW0 = s_wire_at_bit(4), SLW1 = s_wire_at_bit(5), SLW2 = s_wire_at_bit(6),
              SLW3 = s_wire_at_bit(7), SLW4 = s_wire_at_bit(8), SLW5 = s_wire_at_bit(9);

// ---------------- FAST program: Clifford-tracked, CNOT-free ------------------
// amp_logical[i] = st[Phi i].  CNOT(c,t): Phi'=Phi*g (col c ^= col t),
// Phi'^-1 = g*Phi^-1 (row t ^= row c).  Rotation on wire w: xor-vector
// v = Phi col w; side(p) = parity(p & r), r = Phi^-1 row w.

struct Prog {
  int nrot;
  int rty[N_OPS], raidx[N_OPS], rvs[N_OPS], rvl[N_OPS], rrs[N_OPS], rrl[N_OPS];
  int tvs[N_WIRES], tvl[N_WIRES], trs[N_WIRES], trl[N_WIRES];
  int mrs[N_WIRES], mrl[N_WIRES];
  int pos[N_WIRES];            // wire -> physical bit (0..3 slot, 4..9 lane)
  bool ok;
};

constexpr Prog make_prog() {
  Prog P{};
  P.ok = true;
  int phi[N_WIRES], pir[N_WIRES];
  for (int w = 0; w < N_WIRES; ++w) { phi[w] = 1 << w; pir[w] = 1 << w; }
  int n = 0;
  int gt[N_OPS] = {}, ga[N_OPS] = {}, gv[N_OPS] = {}, gr[N_OPS] = {};
  for (int k = 0; k < N_OPS; ++k) {
    if (RAW.ty[k] == 3) {
      const int c = RAW.w0[k], t = RAW.w1[k];
      phi[c] ^= phi[t];        // Phi columns
      pir[t] ^= pir[c];        // Phi^-1 rows
    } else {
      gt[n] = RAW.ty[k]; ga[n] = 10 + k;
      gv[n] = phi[RAW.w0[k]]; gr[n] = pir[RAW.w0[k]];
      ++n;
    }
  }
  P.nrot = n;
  // validate Phi * Phi^-1 == I  (parity(pir[u] & phi[v]) == delta_uv)
  for (int u = 0; u < N_WIRES; ++u)
    for (int v = 0; v < N_WIRES; ++v) {
      const int par = __builtin_popcount((unsigned)(pir[u] & phi[v])) & 1;
      if (par != (u == v ? 1 : 0)) P.ok = false;
    }
  // choose 4 slot bits minimizing lane-crossing gates (exhaustive over C(10,4))
  int bestS = 15; long long bestC = (1LL << 60);
  for (int S = 0; S < 1024; ++S) {
    if (__builtin_popcount((unsigned)S) != 4) continue;
    long long c = 0;
    for (int i = 0; i < n; ++i)
      if (gt[i] != 2 && (gv[i] & ~S & 1023)) c += 32;
    for (int w = 0; w < N_WIRES; ++w)
      if (phi[w] & ~S & 1023) c += 32;
    if (c < bestC) { bestC = c; bestS = S; }
  }
  { int sp = 0;
    for (int w = 0; w < N_WIRES; ++w) if ((bestS >> w) & 1) P.pos[w] = sp++; }
  // lane wires: least-frequent (in crossing masks) gets physical bit 9 (permlane32)
  int freq[N_WIRES] = {};
  for (int i = 0; i < n; ++i)
    if (gt[i] != 2 && (gv[i] & ~bestS & 1023))
      for (int w = 0; w < N_WIRES; ++w)
        if (((gv[i] >> w) & 1) && !((bestS >> w) & 1)) freq[w]++;
  for (int w = 0; w < N_WIRES; ++w)
    if (phi[w] & ~bestS & 1023)
      for (int y = 0; y < N_WIRES; ++y)
        if (((phi[w] >> y) & 1) && !((bestS >> y) & 1)) freq[y]++;
  int minw = -1;
  for (int w = 0; w < N_WIRES; ++w)
    if (!((bestS >> w) & 1) && (minw < 0 || freq[w] < freq[minw])) minw = w;
  { int lp = 4;
    for (int w = 0; w < N_WIRES; ++w)
      if (!((bestS >> w) & 1)) { P.pos[w] = (w == minw) ? 9 : lp++; } }
  // map all masks through pos[]
  auto mp = [&](int m) {
    int r2 = 0;
    for (int w = 0; w < N_WIRES; ++w) if ((m >> w) & 1) r2 |= 1 << P.pos[w];
    return r2;
  };
  for (int i = 0; i < n; ++i) {
    const int v = mp(gv[i]), r2 = mp(gr[i]);
    P.rty[i] = gt[i]; P.raidx[i] = ga[i];
    P.rvs[i] = v & 15; P.rvl[i] = v >> 4;
    P.rrs[i] = r2 & 15; P.rrl[i] = r2 >> 4;
    if (v == 0 || r2 == 0) P.ok = false;
    if ((__builtin_popcount((unsigned)(v & r2)) & 1) == 0) P.ok = false;  // pair sides must differ
  }
  for (int w = 0; w < N_WIRES; ++w) {
    const int v = mp(phi[w]), r2 = mp(pir[w]);
    P.tvs[w] = v & 15; P.tvl[w] = v >> 4;
    P.trs[w] = r2 & 15; P.trl[w] = r2 >> 4;
    P.mrs[w] = r2 & 15; P.mrl[w] = r2 >> 4;
    if (v == 0 || r2 == 0) P.ok = false;
    if ((__builtin_popcount((unsigned)(v & r2)) & 1) == 0) P.ok = false;
  }
  return P;
}

constexpr Prog PROG = make_prog();
static_assert(PROG.ok, "Clifford tracking invariant violated");

// --------------------------------- device ------------------------------------

struct Ctx { int lane; bool s32; };
struct U2t { float ty, tx, A, s; };   // tail V = RY*RX/(cy*cx)

__device__ inline f2 fswap(f2 v) { return __builtin_shufflevector(v, v, 1, 0); }

__device__ inline float bcast(float x, int l) {
  return __int_as_float(__builtin_amdgcn_readlane(__float_as_int(x), l));
}

// fast lane xor-exchange by arbitrary mask 1..63 (probe-validated mechanisms)
template <int VL>
__device__ inline float lxf(float x, const Ctx& cx) {
  static_assert(VL >= 1 && VL <= 63, "");
  if constexpr (VL == 1) {
    return __int_as_float(__builtin_amdgcn_update_dpp(0, __float_as_int(x), 0xB1, 0xF, 0xF, true));
  } else if constexpr (VL == 2) {
    return __int_as_float(__builtin_amdgcn_update_dpp(0, __float_as_int(x), 0x4E, 0xF, 0xF, true));
  } else if constexpr (VL < 32) {
    return __int_as_float(__builtin_amdgcn_ds_swizzle(__float_as_int(x), (VL << 10) | 0x1F));
  } else {
    float t;
#if __has_builtin(__builtin_amdgcn_permlane32_swap)
    {
      auto r = __builtin_amdgcn_permlane32_swap(__float_as_int(x), __float_as_int(x), false, false);
      t = __int_as_float(cx.s32 ? r[0] : r[1]);
    }
#else
    t = __shfl_xor(x, 32, 64);
#endif
    if constexpr ((VL & 31) != 0)
      return __int_as_float(__builtin_amdgcn_ds_swizzle(__float_as_int(t), ((VL & 31) << 10) | 0x1F));
    else
      return t;
  }
}
template <int VL>
__device__ inline f2 lxf2(f2 v, const Ctx& cx) {
  f2 r; r.x = lxf<VL>(v.x, cx); r.y = lxf<VL>(v.y, cx); return r;
}

// SAFE exchange
template <int M>
__device__ inline float sshfl(float x) { return __shfl_xor(x, M, 64); }
template <int M>
__device__ inline f2 sshfl2(f2 v) { f2 r; r.x = sshfl<M>(v.x); r.y = sshfl<M>(v.y); return r; }

template <int RL>
__device__ inline bool lpar6(const bool (&lb)[6]) {
  bool p = false;
  if constexpr (RL & 1)  p ^= lb[0];
  if constexpr (RL & 2)  p ^= lb[1];
  if constexpr (RL & 4)  p ^= lb[2];
  if constexpr (RL & 8)  p ^= lb[3];
  if constexpr (RL & 16) p ^= lb[4];
  if constexpr (RL & 32) p ^= lb[5];
  return p;
}

// ---------------- FAST gates: tau-form with generalized xor-masks ------------

template <int TY, int VS, int VL, int RS, int RL>
__device__ inline void rot_fast(f2 (&st)[16], float tau, const Ctx& cx, const bool (&lb)[6]) {
  if constexpr (TY == 2) {            // RZ: diagonal, only side parity matters
    const bool lp_ = lpar6<RL>(lb);
    const f2 tn = {tau, -tau}, tnn = {-tau, tau};
    const f2 tA = lp_ ? tnn : tn;     // slots with spar==0
    const f2 tB = lp_ ? tn : tnn;     // slots with spar==1
    #pragma unroll
    for (int j = 0; j < 16; ++j) {
      const f2 t = (__builtin_popcount((unsigned)(j & RS)) & 1) ? tB : tA;
      st[j] = st[j] + t * fswap(st[j]);
    }
  } else if constexpr (TY == 0) {     // RX: symmetric, no side needed
    const f2 tn = {tau, -tau};
    #pragma unroll
    for (int j = 0; j < 16; ++j) {
      if constexpr (VS != 0) { if (j & (VS & -VS)) continue; }  // canonical half
      const int j2 = j ^ VS;
      f2 pj, pj2;
      if constexpr (VL != 0) {
        pj = lxf2<VL>(st[j2], cx);
        if constexpr (VS != 0) pj2 = lxf2<VL>(st[j], cx);
      } else { pj = st[j2]; pj2 = st[j]; }
      st[j] = st[j] + tn * fswap(pj);
      if constexpr (VS != 0) st[j2] = st[j2] + tn * fswap(pj2);
    }
  } else {                            // RY: sign = side ? +tau : -tau
    const bool lp_ = lpar6<RL>(lb);
    const f2 tp = {tau, tau}, tm = {-tau, -tau};
    const f2 sA = lp_ ? tp : tm;      // spar==0
    const f2 sB = lp_ ? tm : tp;      // spar==1
    #pragma unroll
    for (int j = 0; j < 16; ++j) {
      if constexpr (VS != 0) { if (j & (VS & -VS)) continue; }
      const int j2 = j ^ VS;
      f2 pj, pj2;
      if constexpr (VL != 0) {
        pj = lxf2<VL>(st[j2], cx);
        if constexpr (VS != 0) pj2 = lxf2<VL>(st[j], cx);
      } else { pj = st[j2]; pj2 = st[j]; }
      const f2 s1 = (__builtin_popcount((unsigned)(j & RS)) & 1) ? sB : sA;
      st[j] = st[j] + s1 * pj;
      if constexpr (VS != 0) {
        const f2 s2_ = (__builtin_popcount((unsigned)(j2 & RS)) & 1) ? sB : sA;
        st[j2] = st[j2] + s2_ * pj2;
      }
    }
  }
}

// tail V: v00=1+iA v01=-ty-itx v10=ty-itx v11=1-iA  (A=ty*tx)
template <int VS, int VL, int RS, int RL>
__device__ inline void tail_fast(f2 (&st)[16], const U2t& u, const Ctx& cx, const bool (&lb)[6]) {
  const bool lp_ = lpar6<RL>(lb);
  const f2 TpP = {u.ty, u.ty}, TpM = {-u.ty, -u.ty};
  const f2 TsP = {u.A, -u.A},  TsM = {-u.A, u.A};
  const f2 Xs  = {u.tx, -u.tx};
  const f2 TpA = lp_ ? TpP : TpM, TpB = lp_ ? TpM : TpP;
  const f2 TsA = lp_ ? TsP : TsM, TsB = lp_ ? TsM : TsP;
  #pragma unroll
  for (int j = 0; j < 16; ++j) {
    if constexpr (VS != 0) { if (j & (VS & -VS)) continue; }
    const int j2 = j ^ VS;
    f2 pj, pj2;
    if constexpr (VL != 0) {
      pj = lxf2<VL>(st[j2], cx);
      if constexpr (VS != 0) pj2 = lxf2<VL>(st[j], cx);
    } else { pj = st[j2]; pj2 = st[j]; }
    {
      const bool sp = __builtin_popcount((unsigned)(j & RS)) & 1;
      const f2 a = st[j];
      f2 o = a + (sp ? TpB : TpA) * pj;
      o = o + (sp ? TsB : TsA) * fswap(a);
      o = o + Xs * fswap(pj);
      st[j] = o;
    }
    if constexpr (VS != 0) {
      const bool sp = __builtin_popcount((unsigned)(j2 & RS)) & 1;
      const f2 a = st[j2];
      f2 o = a + (sp ? TpB : TpA) * pj2;
      o = o + (sp ? TsB : TsA) * fswap(a);
      o = o + Xs * fswap(pj2);
      st[j2] = o;
    }
  }
}

template <int K>
__device__ inline void run_rot(f2 (&st)[16], float tc, float ts, const Ctx& cx,
                               float& scale, const bool (&lb)[6]) {
  if constexpr (K < N_OPS) {
    if constexpr (K < PROG.nrot) {
      const float c = bcast(tc, PROG.raidx[K]);
      const float s = bcast(ts, PROG.raidx[K]);
      const float tau = s * __builtin_amdgcn_rcpf(c);
      scale *= c;
      rot_fast<PROG.rty[K], PROG.rvs[K], PROG.rvl[K], PROG.rrs[K], PROG.rrl[K]>(st, tau, cx, lb);
      run_rot<K + 1>(st, tc, ts, cx, scale, lb);
    }
  }
}

template <int W>
__device__ inline void run_tail(f2 (&st)[16], const U2t& u, const Ctx& cx,
                                float& scale, const bool (&lb)[6]) {
  if constexpr (W < N_WIRES) {
    scale *= u.s;
    tail_fast<PROG.tvs[W], PROG.tvl[W], PROG.trs[W], PROG.trl[W]>(st, u, cx, lb);
    run_tail<W + 1>(st, u, cx, scale, lb);
  }
}

// encoder / head helpers (template-unrolled over wires)
template <int W>
__device__ inline void enc_lane(float& lp, const bool (&lb)[6], const float (&ec)[10], const float (&es)[10]) {
  if constexpr (W < N_WIRES) {
    if constexpr (PROG.pos[W] >= 4)
      lp *= lb[PROG.pos[W] - 4] ? es[W] : ec[W];
    enc_lane<W + 1>(lp, lb, ec, es);
  }
}
template <int W>
__device__ inline void enc_slot(float& a, int j, const float (&ec)[10], const float (&es)[10]) {
  if constexpr (W < N_WIRES) {
    if constexpr (PROG.pos[W] < 4)
      a *= ((j >> PROG.pos[W]) & 1) ? es[W] : ec[W];
    enc_slot<W + 1>(a, j, ec, es);
  }
}
template <int W>
__device__ inline void head_lane(float (&h2)[10], const bool (&lb)[6], const float (&hwv)[10]) {
  if constexpr (W < N_WIRES) {
    const bool lp_ = lpar6<PROG.mrl[W]>(lb);
    h2[W] = lp_ ? -hwv[W] : hwv[W];
    head_lane<W + 1>(h2, lb, hwv);
  }
}
template <int W>
__device__ inline void head_shared(float& L, const float (&h2)[10]) {
  if constexpr (W < N_WIRES) {
    if constexpr (PROG.mrs[W] == 0) L += h2[W];
    head_shared<W + 1>(L, h2);
  }
}
template <int W>
__device__ inline void head_slot(float& sw, int j, const float (&h2)[10]) {
  if constexpr (W < N_WIRES) {
    if constexpr (PROG.mrs[W] != 0)
      sw += (__builtin_popcount((unsigned)(j & PROG.mrs[W])) & 1) ? -h2[W] : h2[W];
    head_slot<W + 1>(sw, j, h2);
  }
}

__device__ inline void body_fast(const Ctx& cx, int b, float tc, float ts,
                                 const float* __restrict__ hw, const float* __restrict__ hb,
                                 float* __restrict__ out) {
  const int lane = cx.lane;
  const bool lb[6] = { (bool)((lane >> 0) & 1), (bool)((lane >> 1) & 1), (bool)((lane >> 2) & 1),
                       (bool)((lane >> 3) & 1), (bool)((lane >> 4) & 1), (bool)((lane >> 5) & 1) };
  U2t u;
  {
    const float cxr = bcast(tc, 40), sxr = bcast(ts, 40);
    const float cyr = bcast(tc, 41), syr = bcast(ts, 41);
    u.tx = sxr * __builtin_amdgcn_rcpf(cxr);
    u.ty = syr * __builtin_amdgcn_rcpf(cyr);
    u.A = u.ty * u.tx;
    u.s = cyr * cxr;
  }
  float ec[10], es[10];
  #pragma unroll
  for (int w = 0; w < N_WIRES; ++w) { ec[w] = bcast(tc, w); es[w] = bcast(ts, w); }
  float lpv = 1.0f;
  enc_lane<0>(lpv, lb, ec, es);
  f2 st[16];
  #pragma unroll
  for (int j = 0; j < 16; ++j) {
    float a = lpv;
    enc_slot<0>(a, j, ec, es);
    st[j] = (f2){a, 0.0f};
  }

  float scale = 1.0f;
  run_rot<0>(st, tc, ts, cx, scale, lb);
  run_tail<0>(st, u, cx, scale, lb);

  float hwv[10];
  #pragma unroll
  for (int w = 0; w < N_WIRES; ++w) hwv[w] = hw[w];
  float h2[10];
  head_lane<0>(h2, lb, hwv);
  float L = 0.0f;
  head_shared<0>(L, h2);
  float acc = 0.0f;
  #pragma unroll
  for (int j = 0; j < 16; ++j) {
    float sw = L;
    head_slot<0>(sw, j, h2);
    const f2 q = st[j] * st[j];
    acc += (q.x + q.y) * sw;
  }
  acc *= scale * scale;      // restore deferred gate scalars
  acc += lxf<1>(acc, cx);
  acc += lxf<2>(acc, cx);
  acc += lxf<4>(acc, cx);
  acc += lxf<8>(acc, cx);
  acc += lxf<16>(acc, cx);
  acc += lxf<32>(acc, cx);
  if (lane == 0) {
    const float logit = acc + hb[0] + 1.57079632679489662f;  // + SHIFT
    out[b] = 1.0f / (1.0f + expf(-logit));
  }
}

// ---------------- SAFE path (R9-proven, classic c,s form) --------------------

template <int TY, int P>
__device__ inline void gate_local_cs(f2 (&st)[16], float c, float s) {
  const f2 c2 = {c, c}, s2 = {s, s}, sn = {s, -s};
  #pragma unroll
  for (int b = 0; b < 16; ++b) {
    if ((b >> P) & 1) continue;
    const int i0 = b, i1 = b | (1 << P);
    const f2 a0 = st[i0], a1 = st[i1];
    if constexpr (TY == 0) {
      st[i0] = c2 * a0 + sn * fswap(a1);
      st[i1] = c2 * a1 + sn * fswap(a0);
    } else if constexpr (TY == 1) {
      st[i0] = c2 * a0 - s2 * a1;
      st[i1] = c2 * a1 + s2 * a0;
    } else {
      st[i0] = c2 * a0 + sn * fswap(a0);
      st[i1] = c2 * a1 - sn * fswap(a1);
    }
  }
}

template <int TY, int LB>
__device__ inline void gate_lane_cs(f2 (&st)[16], float c, float s, int lane) {
  const f2 c2 = {c, c};
  if constexpr (TY == 2) {
    const float t = ((lane >> LB) & 1) ? -s : s;
    const f2 tn = {t, -t};
    #pragma unroll
    for (int j = 0; j < 16; ++j) st[j] = c2 * st[j] + tn * fswap(st[j]);
  } else if constexpr (TY == 0) {
    const f2 sn = {s, -s};
    #pragma unroll
    for (int j = 0; j < 16; ++j) {
      const f2 p = sshfl2<(1 << LB)>(st[j]);
      st[j] = c2 * st[j] + sn * fswap(p);
    }
  } else {
    const float sg = ((lane >> LB) & 1) ? s : -s;
    const f2 sg2 = {sg, sg};
    #pragma unroll
    for (int j = 0; j < 16; ++j) {
      const f2 p = sshfl2<(1 << LB)>(st[j]);
      st[j] = c2 * st[j] + sg2 * p;
    }
  }
}

template <int CB, int TB>
__device__ inline void cnot_safe(f2 (&st)[16], int lane) {
  if constexpr (CB < 4 && TB < 4) {
    #pragma unroll
    for (int b = 0; b < 16; ++b) {
      if (((b >> CB) & 1) && !((b >> TB) & 1)) {
        const int j = b | (1 << TB);
        const f2 t = st[b]; st[b] = st[j]; st[j] = t;
      }
    }
  } else if constexpr (CB < 4) {
    constexpr int M = 1 << (TB - 4);
    #pragma unroll
    for (int b = 0; b < 16; ++b) {
      if ((b >> CB) & 1) st[b] = sshfl2<M>(st[b]);
    }
  } else if constexpr (TB < 4) {
    const bool cb = (lane >> (CB - 4)) & 1;
    #pragma unroll
    for (int b = 0; b < 16; ++b) {
      if (!((b >> TB) & 1)) {
        const int j = b | (1 << TB);
        const f2 a0 = st[b], a1 = st[j];
        st[b] = cb ? a1 : a0; st[j] = cb ? a0 : a1;
      }
    }
  } else {
    const bool cb = (lane >> (CB - 4)) & 1;
    constexpr int M = 1 << (TB - 4);
    #pragma unroll
    for (int j = 0; j < 16; ++j) {
      const f2 p = sshfl2<M>(st[j]);
      st[j] = cb ? p : st[j];
    }
  }
}

template <int K>
__device__ inline void run_safe(f2 (&st)[16], float tc, float ts, int lane) {
  if constexpr (K < NG_SAFE) {
    constexpr int ty = FULLS.type[K];
    constexpr int P0 = FULLS.p0[K];
    constexpr int P1 = FULLS.p1[K];
    constexpr int AI = FULLS.aidx[K];
    if constexpr (ty == 3) {
      cnot_safe<P0, P1>(st, lane);
    } else {
      const float c = __shfl(tc, AI, 64);
      const float s = __shfl(ts, AI, 64);
      if constexpr (P0 < 4) gate_local_cs<ty, P0>(st, c, s);
      else                  gate_lane_cs<ty, P0 - 4>(st, c, s, lane);
    }
    run_safe<K + 1>(st, tc, ts, lane);
  }
}

__device__ __attribute__((noinline))
void body_safe(int lane, int b, float tc, float ts,
               const float* __restrict__ hw, const float* __restrict__ hb,
               float* __restrict__ out) {
  float ec[N_WIRES], es[N_WIRES];
  #pragma unroll
  for (int w = 0; w < N_WIRES; ++w) { ec[w] = __shfl(tc, w, 64); es[w] = __shfl(ts, w, 64); }
  float lp = ((lane >> 0) & 1) ? es[SLW0] : ec[SLW0];
  lp *= ((lane >> 1) & 1) ? es[SLW1] : ec[SLW1];
  lp *= ((lane >> 2) & 1) ? es[SLW2] : ec[SLW2];
  lp *= ((lane >> 3) & 1) ? es[SLW3] : ec[SLW3];
  lp *= ((lane >> 4) & 1) ? es[SLW4] : ec[SLW4];
  lp *= ((lane >> 5) & 1) ? es[SLW5] : ec[SLW5];
  f2 st[16];
  #pragma unroll
  for (int sl = 0; sl < 16; ++sl) {
    float a = lp;
    a *= (sl & 1) ? es[SRW0] : ec[SRW0];
    a *= (sl & 2) ? es[SRW1] : ec[SRW1];
    a *= (sl & 4) ? es[SRW2] : ec[SRW2];
    a *= (sl & 8) ? es[SRW3] : ec[SRW3];
    st[sl] = (f2){a, 0.0f};
  }
  run_safe<0>(st, tc, ts, lane);
  float hwv[N_WIRES];
  #pragma unroll
  for (int w = 0; w < N_WIRES; ++w) hwv[w] = hw[w];
  float lw = (((lane >> 0) & 1) ? -hwv[SLW0] : hwv[SLW0])
           + (((lane >> 1) & 1) ? -hwv[SLW1] : hwv[SLW1])
           + (((lane >> 2) & 1) ? -hwv[SLW2] : hwv[SLW2])
           + (((lane >> 3) & 1) ? -hwv[SLW3] : hwv[SLW3])
           + (((lane >> 4) & 1) ? -hwv[SLW4] : hwv[SLW4])
           + (((lane >> 5) & 1) ? -hwv[SLW5] : hwv[SLW5]);
  float acc = 0.0f;
  #pragma unroll
  for (int sl = 0; sl < 16; ++sl) {
    float sw = lw;
    sw += (sl & 1) ? -hwv[SRW0] : hwv[SRW0];
    sw += (sl & 2) ? -hwv[SRW1] : hwv[SRW1];
    sw += (sl & 4) ? -hwv[SRW2] : hwv[SRW2];
    sw += (sl & 8) ? -hwv[SRW3] : hwv[SRW3];
    const f2 q = st[sl] * st[sl];
    acc += (q.x + q.y) * sw;
  }
  acc += sshfl<1>(acc);
  acc += sshfl<2>(acc);
  acc += sshfl<4>(acc);
  acc += sshfl<8>(acc);
  acc += sshfl<16>(acc);
  acc += sshfl<32>(acc);
  if (lane == 0) {
    const float logit = acc + hb[0] + 1.57079632679489662f;
    out[b] = 1.0f / (1.0f + expf(-logit));
  }
}

// ---------------------------------- kernel -----------------------------------

__global__ __launch_bounds__(256)
void qsim_kernel(const float* __restrict__ xb, const float* __restrict__ rxt,
                 const float* __restrict__ ryt, const float* __restrict__ rp,
                 const float* __restrict__ hw, const float* __restrict__ hb,
                 float* __restrict__ out, int bsz) {
  const int lane = threadIdx.x & 63;
  const int b = blockIdx.x * 4 + (threadIdx.x >> 6);  // one wave = one sample
  if (b >= bsz) return;

  float tc, ts;
  {
    float t = 0.0f;
    if (lane < 10)        t = xb[(size_t)b * 10 + lane];
    else if (lane < 40)   t = rp[lane - 10];
    else if (lane == 40)  t = rxt[0];
    else if (lane == 41)  t = ryt[0];
    float s, c;
    sincosf(0.5f * t, &s, &c);
    tc = c; ts = s;
  }

  // ---- mechanism self-test: every exchange class used by the fast path ----
  Ctx cx; cx.lane = lane; cx.s32 = false;
#if __has_builtin(__builtin_amdgcn_permlane32_swap)
  {
    auto r = __builtin_amdgcn_permlane32_swap(lane, lane, false, false);
    const bool f32 = (((lane & 32) ? r[0] : r[1]) != (lane ^ 32));
    cx.s32 = (((lane & 32) != 0) ^ f32);
  }
#endif
  bool ok = true;
  ok &= (__float_as_int(lxf<1 >(__int_as_float(lane), cx)) == (lane ^ 1));   // DPP
  ok &= (__float_as_int(lxf<2 >(__int_as_float(lane), cx)) == (lane ^ 2));   // DPP
  ok &= (__float_as_int(lxf<5 >(__int_as_float(lane), cx)) == (lane ^ 5));   // swizzle multi-bit
  ok &= (__float_as_int(lxf<16>(__int_as_float(lane), cx)) == (lane ^ 16));  // swizzle
  ok &= (__float_as_int(lxf<31>(__int_as_float(lane), cx)) == (lane ^ 31));  // swizzle full
  ok &= (__float_as_int(lxf<32>(__int_as_float(lane), cx)) == (lane ^ 32));  // permlane32
  ok &= (__float_as_int(lxf<53>(__int_as_float(lane), cx)) == (lane ^ 53));  // composite
  const bool fast = (__all((int)ok) != 0);

  if (fast) body_fast(cx, b, tc, ts, hw, hb, out);
  else      body_safe(lane, b, tc, ts, hw, hb, out);
}

// ---------------------------------- launch -----------------------------------

extern "C" void kernel_launch(void* const* d_in, const int* in_sizes, int n_in,
                              void* d_out, int out_size, void* d_ws, size_t ws_size,
                              hipStream_t stream) {
  const float* xb  = (const float*)d_in[0];
  const float* rxt = (const float*)d_in[1];
  const float* ryt = (const float*)d_in[2];
  const float* rp  = (const float*)d_in[3];
  const float* hw  = (const float*)d_in[4];
  const float* hb  = (const float*)d_in[5];
  float* out = (float*)d_out;

  const int bsz = in_sizes[0] / N_WIRES;
  const int nblk = (bsz + 3) / 4;

  hipLaunchKernelGGL(qsim_kernel, dim3(nblk), dim3(256), 0, stream,
                     xb, rxt, ryt, rp, hw, hb, out, bsz);
}